// Round 7
// baseline (86.723 us; speedup 1.0000x reference)
//
#include <hip/hip_runtime.h>
#include <hip/hip_bf16.h>
#include <math.h>

#define T_LEN   7680
#define NSEG    59
#define NBINS   45

using bf16x8 = __attribute__((ext_vector_type(8))) short;
using f32x4  = __attribute__((ext_vector_type(4))) float;

__device__ __forceinline__ unsigned f2bf(float f) {
    unsigned u = __builtin_bit_cast(unsigned, f);
    return (u + 0x7FFFu + ((u >> 16) & 1u)) >> 16;   // RNE fp32->bf16
}

// Basis table mt[96][256] bf16, GEMM runs on RAW x (detrend+window folded in):
//   col j=2i   : w_n*cos(2pi(i+1)n/256)      (i=0..44)
//   col j=2i+1 : -w_n*sin(2pi(i+1)n/256)
//   col 0 ALSO adds +0.25: exact detrend correction for k=1 real part, since
//   FFT_k(w*(x-mu)) = A_k - mu*W_k, W_1=-64, mu=S/256 -> Y1re = A1re + S/4.
//   All other bins unaffected by detrend (W_k=0 for |k|>=2; Im W_1 = 0).
__global__ void build_basis_kernel(unsigned short* __restrict__ mt) {
    int j = blockIdx.x, n = threadIdx.x;
    const float TH = 0.02454369260617026f;           // 2*pi/256
    float w = 0.5f - 0.5f * cosf((float)n * TH);     // periodic hann
    float v = 0.f;
    if (j < 90) {
        int k = (j >> 1) + 1;
        int m = (k * n) & 255;                       // exact periodic reduction
        float th = (float)m * TH;
        v = (j & 1) ? (-w * sinf(th)) : (w * cosf(th));
        if (j == 0) v += 0.25f;                      // fold detrend into k=1 re
    }
    mt[j * 256 + n] = (unsigned short)f2bf(v);
}

// 2 channels per block, lb(256,3) (lb4 caused 20MB scratch spill in R6).
// Phase S/G/E bodies are R2/R6-verbatim (proven). Guards NEVER inside the
// k0 MFMA loop (R3-R5 conviction). Prefetch of ch1's x sits between G and E
// of ch0: register-only, no LDS/barrier interaction.
__global__ __launch_bounds__(256, 3)
void welch_main_kernel(const float* __restrict__ x,
                       const unsigned short* __restrict__ mt,
                       float* __restrict__ out) {
    __shared__ __align__(16) unsigned short Sm[64 * 256];  // 32 KB, swizzled rows
    __shared__ float psum[96];

    const int tid  = threadIdx.x;
    const int lane = tid & 63;
    const int w    = tid >> 6;
    const int ch0  = blockIdx.x * 2;
    const float* gx = x + (size_t)ch0 * T_LEN;

    // ---- hoisted x loads for ch0: all 8 in flight before any use
    f32x4 xv[8];
    #pragma unroll
    for (int i = 0; i < 8; ++i) {
        int c = i * 256 + tid;
        if (c < 1920) xv[i] = *reinterpret_cast<const f32x4*>(gx + 4 * c);
    }

    // ---- B fragments (overlap their L2 latency with the x loads above).
    // Wave w owns MFMA pairs p=6w..6w+5, p = ct*4 + rt; ctA=(6w)>>2, ctB=(6w+5)>>2.
    const int ctA = (6 * w) >> 2;
    const int ctB = (6 * w + 5) >> 2;
    const int col0 = lane & 15;
    const int kq   = (lane >> 4) * 8;
    bf16x8 bregA[8], bregB[8];
    #pragma unroll
    for (int k0 = 0; k0 < 8; ++k0) {
        bregA[k0] = *reinterpret_cast<const bf16x8*>(
            mt + (ctA * 16 + col0) * 256 + k0 * 32 + kq);
        bregB[k0] = *reinterpret_cast<const bf16x8*>(
            mt + (ctB * 16 + col0) * 256 + k0 * 32 + kq);
    }

    #pragma unroll
    for (int cc = 0; cc < 2; ++cc) {
        const int ch = ch0 + cc;

        if (tid < 96) psum[tid] = 0.f;

        // ---- phase S (R2-verbatim addressing): convert xv -> bf16, dual write.
        #pragma unroll
        for (int i = 0; i < 8; ++i) {
            int c = i * 256 + tid;
            if (c < 1920) {
                unsigned b0 = f2bf(xv[i][0]), b1 = f2bf(xv[i][1]);
                unsigned b2 = f2bf(xv[i][2]), b3 = f2bf(xv[i][3]);
                uint2 pk; pk.x = b0 | (b1 << 16); pk.y = b2 | (b3 << 16);
                int hh = c >> 5, q = c & 31;
                if (hh < NSEG) {
                    unsigned a = (unsigned)(hh * 512 + 8 * q) ^ (unsigned)((hh & 7) << 4);
                    *reinterpret_cast<uint2*>((char*)Sm + a) = pk;
                }
                if (hh > 0) {
                    int s = hh - 1;
                    unsigned a = (unsigned)(s * 512 + 256 + 8 * q) ^ (unsigned)((s & 7) << 4);
                    *reinterpret_cast<uint2*>((char*)Sm + a) = pk;
                }
            }
        }
        if (cc == 0) {
            // zero rows 59..63 once; chunk path never writes them -> stays zero
            for (int z = tid; z < 320; z += 256) {
                int row = 59 + (z >> 6), q = z & 63;
                unsigned a = (unsigned)(row * 512 + 8 * q) ^ (unsigned)((row & 7) << 4);
                *reinterpret_cast<uint2*>((char*)Sm + a) = make_uint2(0u, 0u);
            }
        }
        __syncthreads();

        // ---- phase G (R2-VERBATIM: a[8] array, guards OUTSIDE k0 loop)
        f32x4 accA[4], accB[4];
        #pragma unroll
        for (int r = 0; r < 4; ++r) {
            accA[r] = (f32x4){0.f, 0.f, 0.f, 0.f};
            accB[r] = (f32x4){0.f, 0.f, 0.f, 0.f};
        }
        const unsigned kq16 = (unsigned)((lane >> 4) * 16);
        #pragma unroll
        for (int rt = 0; rt < 4; ++rt) {
            const int arow = rt * 16 + (lane & 15);
            const unsigned abase = (unsigned)arow * 512u;
            const unsigned aswz  = (unsigned)((arow & 7) << 4);
            bf16x8 a[8];
            #pragma unroll
            for (int k0 = 0; k0 < 8; ++k0)
                a[k0] = *reinterpret_cast<const bf16x8*>(
                    (char*)Sm + ((abase + (unsigned)k0 * 64u + kq16) ^ aswz));
            const bool oA = (unsigned)(ctA * 4 + rt - 6 * w) < 6u;
            const bool oB = (unsigned)(ctB * 4 + rt - 6 * w) < 6u;
            if (oA) {
                #pragma unroll
                for (int k0 = 0; k0 < 8; ++k0)
                    accA[rt] = __builtin_amdgcn_mfma_f32_16x16x32_bf16(
                        a[k0], bregA[k0], accA[rt], 0, 0, 0);
            }
            if (oB && ctB != ctA) {
                #pragma unroll
                for (int k0 = 0; k0 < 8; ++k0)
                    accB[rt] = __builtin_amdgcn_mfma_f32_16x16x32_bf16(
                        a[k0], bregB[k0], accB[rt], 0, 0, 0);
            }
        }

        // ---- prefetch next channel's x (register-only; hides HBM latency
        // under phase E + output + next staging converts)
        if (cc == 0) {
            const float* gx1 = gx + T_LEN;
            #pragma unroll
            for (int i = 0; i < 8; ++i) {
                int c = i * 256 + tid;
                if (c < 1920) xv[i] = *reinterpret_cast<const f32x4*>(gx1 + 4 * c);
            }
        }

        // ---- phase E (R2-verbatim)
        {
            float pA = 0.f, pB = 0.f;
            #pragma unroll
            for (int rt = 0; rt < 4; ++rt) {
                if ((unsigned)(ctA * 4 + rt - 6 * w) < 6u)
                    pA += accA[rt][0]*accA[rt][0] + accA[rt][1]*accA[rt][1]
                        + accA[rt][2]*accA[rt][2] + accA[rt][3]*accA[rt][3];
                if ((unsigned)(ctB * 4 + rt - 6 * w) < 6u && ctB != ctA)
                    pB += accB[rt][0]*accB[rt][0] + accB[rt][1]*accB[rt][1]
                        + accB[rt][2]*accB[rt][2] + accB[rt][3]*accB[rt][3];
            }
            pA += __shfl_xor(pA, 16);  pA += __shfl_xor(pA, 32);
            pB += __shfl_xor(pB, 16);  pB += __shfl_xor(pB, 32);
            if (lane < 16) {
                atomicAdd(&psum[ctA * 16 + col0], pA);
                if (ctB != ctA) atomicAdd(&psum[ctB * 16 + col0], pB);
            }
        }
        __syncthreads();

        // ---- output
        if (tid < NBINS) {
            const float CNORM = 2.0f / (24576.0f * 59.0f);  // fs*sum(w^2) = 256*96
            float psd = (psum[2 * tid] + psum[2 * tid + 1]) * CNORM;
            out[(size_t)ch * NBINS + tid] = log1pf(psd);
        }
        __syncthreads();   // psum read before next iteration zeroes it
    }
}

extern "C" void kernel_launch(void* const* d_in, const int* in_sizes, int n_in,
                              void* d_out, int out_size, void* d_ws, size_t ws_size,
                              hipStream_t stream) {
    const float* x = (const float*)d_in[0];
    float* out = (float*)d_out;
    unsigned short* mt = (unsigned short*)d_ws;   // 96*256*2 = 49152 B

    build_basis_kernel<<<96, 256, 0, stream>>>(mt);
    welch_main_kernel<<<2048, 256, 0, stream>>>(x, mt, out);
}